// Round 5
// baseline (175.012 us; speedup 1.0000x reference)
//
#include <hip/hip_runtime.h>
#include <stdint.h>

#define JAX_PARTITIONABLE 1

constexpr int N = 4096;
constexpr int DIM = 64;
constexpr int TOPK = 5;
constexpr int NEGS = 20;
constexpr float TAU_ = 0.1f;
constexpr uint32_t SPAN = 4091u;   // N - TOPK
constexpr uint32_t MULT = 2309u;   // ((1<<16) % SPAN)^2 % SPAN

constexpr int CQ = 512;            // cols per wave (col-eighth)
constexpr int NQ = N / CQ;         // 8 col groups
constexpr int NT = CQ / 16;        // 32 tiles per wave

typedef __attribute__((ext_vector_type(8))) short bf16x8;
typedef __attribute__((ext_vector_type(4))) float f32x4;

__device__ __forceinline__ uint32_t rotl32(uint32_t v, int d) {
  return (v << d) | (v >> (32 - d));
}

// Threefry-2x32, 20 rounds, exactly as jax/_src/prng.py lowering.
__device__ __forceinline__ void threefry(uint32_t k0, uint32_t k1,
                                         uint32_t& x0, uint32_t& x1) {
  const uint32_t k2 = k0 ^ k1 ^ 0x1BD11BDAu;
  x0 += k0; x1 += k1;
#define TF_R(r) { x0 += x1; x1 = rotl32(x1, r); x1 ^= x0; }
  TF_R(13) TF_R(15) TF_R(26) TF_R(6)
  x0 += k1; x1 += k2 + 1u;
  TF_R(17) TF_R(29) TF_R(16) TF_R(24)
  x0 += k2; x1 += k0 + 2u;
  TF_R(13) TF_R(15) TF_R(26) TF_R(6)
  x0 += k0; x1 += k1 + 3u;
  TF_R(17) TF_R(29) TF_R(16) TF_R(24)
  x0 += k1; x1 += k2 + 4u;
  TF_R(13) TF_R(15) TF_R(26) TF_R(6)
  x0 += k2; x1 += k0 + 5u;
#undef TF_R
}

__device__ __forceinline__ uint32_t sample_idx(uint32_t seed, uint32_t f) {
#if JAX_PARTITIONABLE
  uint32_t a0 = 0u, a1 = 0u; threefry(0u, seed, a0, a1);   // k1 = enc(key,(0,0))
  uint32_t b0 = 0u, b1 = 1u; threefry(0u, seed, b0, b1);   // k2 = enc(key,(0,1))
  uint32_t h0 = 0u, h1 = f;  threefry(a0, a1, h0, h1);
  const uint32_t hi = h0 ^ h1;
  uint32_t l0 = 0u, l1 = f;  threefry(b0, b1, l0, l1);
  const uint32_t lo = l0 ^ l1;
#else
  uint32_t a0 = 0u, a1 = 2u; threefry(0u, seed, a0, a1);
  uint32_t c0 = 1u, c1 = 3u; threefry(0u, seed, c0, c1);
  const uint32_t HALF = (uint32_t)(N * NEGS / 2);
  uint32_t hi, lo;
  if (f < HALF) {
    uint32_t x0 = f, x1 = f + HALF; threefry(a0, c0, x0, x1); hi = x0;
    x0 = f; x1 = f + HALF;          threefry(a1, c1, x0, x1); lo = x0;
  } else {
    uint32_t x0 = f - HALF, x1 = f; threefry(a0, c0, x0, x1); hi = x1;
    x0 = f - HALF; x1 = f;          threefry(a1, c1, x0, x1); lo = x1;
  }
#endif
  return ((hi % SPAN) * MULT + (lo % SPAN)) % SPAN;
}

__device__ __forceinline__ float acosh_dev(float z) {
  return logf(z + sqrtf((z - 1.0f) * (z + 1.0f)));
}

__device__ __forceinline__ uint16_t f2bf(float f) {   // RNE f32 -> bf16
  const uint32_t u = __float_as_uint(f);
  return (uint16_t)((u + 0x7FFFu + ((u >> 16) & 1u)) >> 16);
}
__device__ __forceinline__ float bf2f(uint16_t h) {
  return __uint_as_float((uint32_t)h << 16);
}

// K_pre: per row: exact f32 norms + inv, and bf16 hi/lo split rows
// Xs layout: [mod][row][128 u16] = hi[64] | lo[64], row stride 256 B.
__global__ __launch_bounds__(64) void k_pre(const float* __restrict__ Xa,
                                            const float* __restrict__ Xt,
                                            uint16_t* __restrict__ Xs,
                                            float* __restrict__ ysq,
                                            float* __restrict__ inv) {
  const int m = blockIdx.y;                  // 0 = text, 1 = audio
  const float* __restrict__ X = (m == 0) ? Xt : Xa;
  const int i = blockIdx.x * 64 + threadIdx.x;
  const float* xr = X + (size_t)i * DIM;

  uint32_t hb[DIM / 2], lb[DIM / 2];
  float s = 0.0f;
#pragma unroll
  for (int u = 0; u < DIM / 4; ++u) {
    const float4 v = *(const float4*)(xr + 4 * u);
    s = fmaf(v.x, v.x, s); s = fmaf(v.y, v.y, s);
    s = fmaf(v.z, v.z, s); s = fmaf(v.w, v.w, s);
    const uint16_t h0 = f2bf(v.x), h1 = f2bf(v.y), h2 = f2bf(v.z), h3 = f2bf(v.w);
    const uint16_t l0 = f2bf(v.x - bf2f(h0)), l1 = f2bf(v.y - bf2f(h1));
    const uint16_t l2 = f2bf(v.z - bf2f(h2)), l3 = f2bf(v.w - bf2f(h3));
    hb[2 * u]     = (uint32_t)h0 | ((uint32_t)h1 << 16);
    hb[2 * u + 1] = (uint32_t)h2 | ((uint32_t)h3 << 16);
    lb[2 * u]     = (uint32_t)l0 | ((uint32_t)l1 << 16);
    lb[2 * u + 1] = (uint32_t)l2 | ((uint32_t)l3 << 16);
  }
  uint32_t* dst = (uint32_t*)(Xs + (size_t)(m * N + i) * 128);
#pragma unroll
  for (int w = 0; w < 8; ++w) {
    uint4 qh = { hb[4 * w], hb[4 * w + 1], hb[4 * w + 2], hb[4 * w + 3] };
    ((uint4*)dst)[w] = qh;
  }
#pragma unroll
  for (int w = 0; w < 8; ++w) {
    uint4 ql = { lb[4 * w], lb[4 * w + 1], lb[4 * w + 2], lb[4 * w + 3] };
    ((uint4*)dst)[8 + w] = ql;
  }
  ysq[m * N + i] = s;
  inv[m * N + i] = 1.0f / (1.0f - fminf(s, 1.0f));
}

// K1: MFMA pairwise-z + per-row top-5 partials.
// One wave per block. Wave owns 16 rows x 512 cols (one col-eighth).
// dot = Ahi*Bhi + Ahi*Blo + Alo*Bhi via mfma_f32_16x16x32_bf16 (6 mfma/tile).
// grid (256 row-blocks, 8 eighths, 2 mods) = 4096 waves = 4 waves/SIMD.
__global__ __launch_bounds__(64, 4) void k_top5(
    const uint16_t* __restrict__ Xs, const float* __restrict__ ysq,
    const float* __restrict__ inv, uint64_t* __restrict__ partial) {
  const int m = blockIdx.z;
  const int qq = blockIdx.y;
  const int i0 = blockIdx.x * 16;
  const int j0q = qq * CQ;
  const int mN = m * N;
  const uint16_t* __restrict__ Xm = Xs + (size_t)m * N * 128;
  const int l = (int)threadIdx.x;
  const int lc = l & 15;          // A-row / B-col lane index
  const int lk = l >> 4;          // k-chunk group
  const int lk4 = lk * 4;         // C-row base for this lane
  const int lk8 = lk * 8;         // u16 offset of this lane's 8 bf16

  // A fragments: af[k-chunk][hi/lo]
  bf16x8 af[2][2];
#pragma unroll
  for (int c = 0; c < 2; ++c)
#pragma unroll
    for (int h = 0; h < 2; ++h)
      af[c][h] = *(const bf16x8*)(Xm + (size_t)(i0 + lc) * 128 +
                                  h * 64 + c * 32 + lk8);

  float xsq_r[4], inv_r[4];
#pragma unroll
  for (int p = 0; p < 4; ++p) {
    const int gi = i0 + lk4 + p;
    xsq_r[p] = ysq[mN + gi];
    inv_r[p] = inv[mN + gi];
  }

  // sentinel: z=+inf, idx=0xFFFFFFFF (never selected over any real z)
  const uint64_t SENT = ((uint64_t)0x7F800000u << 32) | 0xFFFFFFFFu;
  uint64_t t5[4][TOPK];
  float z5[4];
#pragma unroll
  for (int e = 0; e < 4; ++e) {
    z5[e] = __uint_as_float(0x7F800000u);   // +inf
#pragma unroll
    for (int t = 0; t < TOPK; ++t) t5[e][t] = SENT;
  }

  const f32x4 zz = {0.0f, 0.0f, 0.0f, 0.0f};

#define LOADB(BF, YC, IC, T)                                                   \
  {                                                                            \
    const uint16_t* bp = Xm + (size_t)(j0q + (T) * 16 + lc) * 128 + lk8;       \
    BF[0][0] = *(const bf16x8*)(bp);                                           \
    BF[1][0] = *(const bf16x8*)(bp + 32);                                      \
    BF[0][1] = *(const bf16x8*)(bp + 64);                                      \
    BF[1][1] = *(const bf16x8*)(bp + 96);                                      \
    YC = ysq[mN + j0q + (T) * 16 + lc];                                        \
    IC = inv[mN + j0q + (T) * 16 + lc];                                        \
  }

  // accumulation chain order identical to round-3 kernel (bit-exact)
#define MFMA_TILE(ACC, BF)                                                     \
  {                                                                            \
    ACC = __builtin_amdgcn_mfma_f32_16x16x32_bf16(af[0][0], BF[0][0], zz, 0, 0, 0);  \
    ACC = __builtin_amdgcn_mfma_f32_16x16x32_bf16(af[1][0], BF[1][0], ACC, 0, 0, 0); \
    ACC = __builtin_amdgcn_mfma_f32_16x16x32_bf16(af[0][0], BF[0][1], ACC, 0, 0, 0); \
    ACC = __builtin_amdgcn_mfma_f32_16x16x32_bf16(af[1][0], BF[1][1], ACC, 0, 0, 0); \
    ACC = __builtin_amdgcn_mfma_f32_16x16x32_bf16(af[0][1], BF[0][0], ACC, 0, 0, 0); \
    ACC = __builtin_amdgcn_mfma_f32_16x16x32_bf16(af[1][1], BF[1][0], ACC, 0, 0, 0); \
  }

#define EPILOG(T, ACC, YC, IC)                                                 \
  {                                                                            \
    const int gj = j0q + (T) * 16 + lc;                                        \
    _Pragma("unroll") for (int p = 0; p < 4; ++p) {                            \
      const int gi = i0 + lk4 + p;                                             \
      const float diff = fmaxf(xsq_r[p] + (YC)-2.0f * ACC[p], 0.0f);           \
      const float z = fmaf(2.0f * (diff * inv_r[p]), (IC), 1.0f);              \
      if (z <= z5[p] && gi != gj) {     /* fast screen vs 5th-best */          \
        uint64_t key = ((uint64_t)__float_as_uint(z) << 32) | (uint32_t)gj;    \
        if (key < t5[p][TOPK - 1]) {                                           \
          _Pragma("unroll") for (int tt = 0; tt < TOPK; ++tt) {                \
            const uint64_t cv = t5[p][tt];                                     \
            if (key < cv) { t5[p][tt] = key; key = cv; }                       \
          }                                                                    \
          z5[p] = __uint_as_float((uint32_t)(t5[p][TOPK - 1] >> 32));          \
        }                                                                      \
      }                                                                        \
    }                                                                          \
  }

  bf16x8 bE[2][2], bO[2][2];
  float ycE, icE, ycO, icO;
  f32x4 accE, accO;

  LOADB(bE, ycE, icE, 0)
  LOADB(bO, ycO, icO, 1)
  MFMA_TILE(accE, bE)

#pragma unroll 1
  for (int t = 1; t < NT; t += 2) {
    const float ycEp = ycE, icEp = icE;
    if (t + 1 < NT) LOADB(bE, ycE, icE, t + 1)
    MFMA_TILE(accO, bO)
    EPILOG(t - 1, accE, ycEp, icEp)
    const float ycOp = ycO, icOp = icO;
    if (t + 2 < NT) LOADB(bO, ycO, icO, t + 2)
    if (t + 1 < NT) MFMA_TILE(accE, bE)
    EPILOG(t, accO, ycOp, icOp)
  }
#undef LOADB
#undef MFMA_TILE
#undef EPILOG

  // cross-lane merge: row r = lk*4+p has 16 contributor lists (lc = 0..15)
  __shared__ uint64_t mbuf[16 * 81];   // stride 81 breaks bank alignment
#pragma unroll
  for (int p = 0; p < 4; ++p)
#pragma unroll
    for (int t = 0; t < TOPK; ++t)
      mbuf[(lk4 + p) * 81 + lc * TOPK + t] = t5[p][t];
  __syncthreads();

  if (l < 16) {
    uint64_t cur[TOPK];
#pragma unroll
    for (int t = 0; t < TOPK; ++t) cur[t] = mbuf[l * 81 + t];
    for (int c = 1; c < 16; ++c) {
      for (int t = 0; t < TOPK; ++t) {
        uint64_t key = mbuf[l * 81 + c * TOPK + t];
        if (key >= cur[TOPK - 1]) break;   // lists sorted ascending
#pragma unroll
        for (int u = 0; u < TOPK; ++u) {
          const uint64_t cv = cur[u];
          if (key < cv) { cur[u] = key; key = cv; }
        }
      }
    }
#pragma unroll
    for (int t = 0; t < TOPK; ++t)
      partial[((size_t)(m * NQ + qq) * N + i0 + l) * TOPK + t] = cur[t];
  }
}

// K2: merge eighth-partials -> top5; exact f32 pos_term recompute;
// threefry sampling + exact negative distances + logsumexp.
__global__ __launch_bounds__(64) void k_neg(const float* __restrict__ Xa,
                                            const float* __restrict__ Xt,
                                            const float* __restrict__ ysq,
                                            const float* __restrict__ inv,
                                            const uint64_t* __restrict__ partial,
                                            float* __restrict__ rowres) {
  const int m = blockIdx.y;
  const int i = blockIdx.x;
  const float* __restrict__ X = (m == 0) ? Xt : Xa;
  const uint32_t seed = (m == 0) ? 1u : 2u;  // key(1)=text, key(2)=audio
  const int lane = threadIdx.x;

  __shared__ float4 xi4[DIM / 4];
  __shared__ float posv[TOPK];
  if (lane < DIM / 4) xi4[lane] = ((const float4*)(X + (size_t)i * DIM))[lane];
  __syncthreads();

  // merge NQ sorted eighth lists (uniform across lanes)
  uint64_t cur[TOPK];
#pragma unroll
  for (int t = 0; t < TOPK; ++t)
    cur[t] = partial[((size_t)(m * NQ) * N + i) * TOPK + t];
  for (int q = 1; q < NQ; ++q) {
    for (int t = 0; t < TOPK; ++t) {
      uint64_t key = partial[((size_t)(m * NQ + q) * N + i) * TOPK + t];
      if (key >= cur[TOPK - 1]) break;
#pragma unroll
      for (int u = 0; u < TOPK; ++u) {
        const uint64_t cv = cur[u];
        if (key < cv) { cur[u] = key; key = cv; }
      }
    }
  }

  const float ysq_i = ysq[m * N + i];
  const float inv_i = inv[m * N + i];

  // lanes 32..36: exact f32 distance for the 5 selected positives
  if (lane >= 32 && lane < 32 + TOPK) {
    const int t = lane - 32;
    const uint32_t c = (uint32_t)(cur[t] & 0xffffffffu);
    const float4* xc = (const float4*)(X + (size_t)c * DIM);
    float dot = 0.0f;
#pragma unroll
    for (int k = 0; k < DIM / 4; ++k) {
      const float4 a = xi4[k];
      const float4 b = xc[k];
      dot = fmaf(a.x, b.x, dot); dot = fmaf(a.y, b.y, dot);
      dot = fmaf(a.z, b.z, dot); dot = fmaf(a.w, b.w, dot);
    }
    const float diff = fmaxf(ysq_i + ysq[m * N + c] - 2.0f * dot, 0.0f);
    const float z = 1.0f + 2.0f * diff * inv_i * inv[m * N + c];
    posv[t] = -acosh_dev(z) / TAU_;
  }

  uint32_t pidx[TOPK];
#pragma unroll
  for (int t = 0; t < TOPK; ++t) pidx[t] = (uint32_t)(cur[t] & 0xffffffffu);

#define CSWAP(a, b)                                                           \
  { const uint32_t mn = pidx[a] < pidx[b] ? pidx[a] : pidx[b];                \
    const uint32_t mx = pidx[a] < pidx[b] ? pidx[b] : pidx[a];                \
    pidx[a] = mn; pidx[b] = mx; }
  CSWAP(0, 1) CSWAP(3, 4) CSWAP(2, 4) CSWAP(2, 3) CSWAP(1, 4)
  CSWAP(0, 3) CSWAP(0, 2) CSWAP(1, 3) CSWAP(1, 2)
#undef CSWAP

  float v = -1e30f;
  if (lane < NEGS) {
    const uint32_t f = (uint32_t)i * (uint32_t)NEGS + (uint32_t)lane;
    uint32_t c = sample_idx(seed, f);
#pragma unroll
    for (int t = 0; t < TOPK; ++t) c += (c >= pidx[t]) ? 1u : 0u;
    if (c != (uint32_t)i) {
      const float4* xc = (const float4*)(X + (size_t)c * DIM);
      float dot = 0.0f;
#pragma unroll
      for (int k = 0; k < DIM / 4; ++k) {
        const float4 a = xi4[k];
        const float4 b = xc[k];
        dot = fmaf(a.x, b.x, dot); dot = fmaf(a.y, b.y, dot);
        dot = fmaf(a.z, b.z, dot); dot = fmaf(a.w, b.w, dot);
      }
      const float diff = fmaxf(ysq_i + ysq[m * N + c] - 2.0f * dot, 0.0f);
      const float z = 1.0f + 2.0f * diff * inv_i * inv[m * N + c];
      v = -acosh_dev(z) / TAU_;
    }
  }

  __syncthreads();   // posv visible

  float vmax = v;
#pragma unroll
  for (int o = 32; o > 0; o >>= 1) vmax = fmaxf(vmax, __shfl_xor(vmax, o, 64));
  float e = expf(v - vmax);
  float ss = e;
#pragma unroll
  for (int o = 32; o > 0; o >>= 1) ss += __shfl_xor(ss, o, 64);

  if (lane == 0) {
    float vm = -1e30f;
#pragma unroll
    for (int t = 0; t < TOPK; ++t) vm = fmaxf(vm, posv[t]);
    float ps = 0.0f;
#pragma unroll
    for (int t = 0; t < TOPK; ++t) ps += expf(posv[t] - vm);
    const float pos = vm + logf(ps);
    rowres[m * N + i] = (vmax + logf(ss)) - pos;
  }
}

// K3: deterministic final reduce (f64 accumulation), out = 0.01 * mean
__global__ __launch_bounds__(256) void k_reduce(const float* __restrict__ rowres,
                                                float* __restrict__ out) {
  __shared__ double sh[256];
  double s = 0.0;
  for (int idx = threadIdx.x; idx < 2 * N; idx += 256) s += (double)rowres[idx];
  sh[threadIdx.x] = s;
  __syncthreads();
  for (int o = 128; o > 0; o >>= 1) {
    if (threadIdx.x < o) sh[threadIdx.x] += sh[threadIdx.x + o];
    __syncthreads();
  }
  if (threadIdx.x == 0) out[0] = (float)(0.01 * (sh[0] / (double)N));
}

extern "C" void kernel_launch(void* const* d_in, const int* in_sizes, int n_in,
                              void* d_out, int out_size, void* d_ws,
                              size_t ws_size, hipStream_t stream) {
  const float* Xa = (const float*)d_in[0];   // audio_embeds
  const float* Xt = (const float*)d_in[1];   // text_embeds
  float* out = (float*)d_out;

  // ws layout (~4.8 MB): ysq[2N] | inv[2N] | partial[2*NQ*N*5 u64] | rowres[2N]
  //                      | Xs[2*N*128 u16]
  float* ysq = (float*)d_ws;
  float* inv = ysq + 2 * N;
  uint64_t* partial = (uint64_t*)(inv + 2 * N);
  float* rowres = (float*)(partial + (size_t)2 * NQ * N * TOPK);
  uint16_t* Xs = (uint16_t*)(rowres + 2 * N);

  k_pre<<<dim3(N / 64, 2), 64, 0, stream>>>(Xa, Xt, Xs, ysq, inv);
  k_top5<<<dim3(N / 16, NQ, 2), 64, 0, stream>>>(Xs, ysq, inv, partial);
  k_neg<<<dim3(N, 2), 64, 0, stream>>>(Xa, Xt, ysq, inv, partial, rowres);
  k_reduce<<<1, 256, 0, stream>>>(rowres, out);
}

// Round 6
// 132.051 us; speedup vs baseline: 1.3253x; 1.3253x over previous
//
#include <hip/hip_runtime.h>
#include <stdint.h>

#define JAX_PARTITIONABLE 1

constexpr int N = 4096;
constexpr int DIM = 64;
constexpr int TOPK = 5;
constexpr int NEGS = 20;
constexpr float TAU_ = 0.1f;
constexpr uint32_t SPAN = 4091u;   // N - TOPK
constexpr uint32_t MULT = 2309u;   // ((1<<16) % SPAN)^2 % SPAN

constexpr int CQ = 512;            // cols per wave (col-eighth)
constexpr int NQ = N / CQ;         // 8 col groups
constexpr int NT = CQ / 16;        // 32 tiles per wave

typedef __attribute__((ext_vector_type(8))) short bf16x8;
typedef __attribute__((ext_vector_type(4))) float f32x4;

__device__ __forceinline__ uint32_t rotl32(uint32_t v, int d) {
  return (v << d) | (v >> (32 - d));
}

// Threefry-2x32, 20 rounds, exactly as jax/_src/prng.py lowering.
__device__ __forceinline__ void threefry(uint32_t k0, uint32_t k1,
                                         uint32_t& x0, uint32_t& x1) {
  const uint32_t k2 = k0 ^ k1 ^ 0x1BD11BDAu;
  x0 += k0; x1 += k1;
#define TF_R(r) { x0 += x1; x1 = rotl32(x1, r); x1 ^= x0; }
  TF_R(13) TF_R(15) TF_R(26) TF_R(6)
  x0 += k1; x1 += k2 + 1u;
  TF_R(17) TF_R(29) TF_R(16) TF_R(24)
  x0 += k2; x1 += k0 + 2u;
  TF_R(13) TF_R(15) TF_R(26) TF_R(6)
  x0 += k0; x1 += k1 + 3u;
  TF_R(17) TF_R(29) TF_R(16) TF_R(24)
  x0 += k1; x1 += k2 + 4u;
  TF_R(13) TF_R(15) TF_R(26) TF_R(6)
  x0 += k2; x1 += k0 + 5u;
#undef TF_R
}

__device__ __forceinline__ uint32_t sample_idx(uint32_t seed, uint32_t f) {
#if JAX_PARTITIONABLE
  uint32_t a0 = 0u, a1 = 0u; threefry(0u, seed, a0, a1);   // k1 = enc(key,(0,0))
  uint32_t b0 = 0u, b1 = 1u; threefry(0u, seed, b0, b1);   // k2 = enc(key,(0,1))
  uint32_t h0 = 0u, h1 = f;  threefry(a0, a1, h0, h1);
  const uint32_t hi = h0 ^ h1;
  uint32_t l0 = 0u, l1 = f;  threefry(b0, b1, l0, l1);
  const uint32_t lo = l0 ^ l1;
#else
  uint32_t a0 = 0u, a1 = 2u; threefry(0u, seed, a0, a1);
  uint32_t c0 = 1u, c1 = 3u; threefry(0u, seed, c0, c1);
  const uint32_t HALF = (uint32_t)(N * NEGS / 2);
  uint32_t hi, lo;
  if (f < HALF) {
    uint32_t x0 = f, x1 = f + HALF; threefry(a0, c0, x0, x1); hi = x0;
    x0 = f; x1 = f + HALF;          threefry(a1, c1, x0, x1); lo = x0;
  } else {
    uint32_t x0 = f - HALF, x1 = f; threefry(a0, c0, x0, x1); hi = x1;
    x0 = f - HALF; x1 = f;          threefry(a1, c1, x0, x1); lo = x1;
  }
#endif
  return ((hi % SPAN) * MULT + (lo % SPAN)) % SPAN;
}

__device__ __forceinline__ float acosh_dev(float z) {
  return logf(z + sqrtf((z - 1.0f) * (z + 1.0f)));
}

__device__ __forceinline__ uint16_t f2bf(float f) {   // RNE f32 -> bf16
  const uint32_t u = __float_as_uint(f);
  return (uint16_t)((u + 0x7FFFu + ((u >> 16) & 1u)) >> 16);
}
__device__ __forceinline__ float bf2f(uint16_t h) {
  return __uint_as_float((uint32_t)h << 16);
}

// K_pre: per row: exact f32 norms + inv, and bf16 hi/lo split rows
// Xs layout: [mod][row][128 u16] = hi[64] | lo[64], row stride 256 B.
__global__ __launch_bounds__(64) void k_pre(const float* __restrict__ Xa,
                                            const float* __restrict__ Xt,
                                            uint16_t* __restrict__ Xs,
                                            float* __restrict__ ysq,
                                            float* __restrict__ inv) {
  const int m = blockIdx.y;                  // 0 = text, 1 = audio
  const float* __restrict__ X = (m == 0) ? Xt : Xa;
  const int i = blockIdx.x * 64 + threadIdx.x;
  const float* xr = X + (size_t)i * DIM;

  uint32_t hb[DIM / 2], lb[DIM / 2];
  float s = 0.0f;
#pragma unroll
  for (int u = 0; u < DIM / 4; ++u) {
    const float4 v = *(const float4*)(xr + 4 * u);
    s = fmaf(v.x, v.x, s); s = fmaf(v.y, v.y, s);
    s = fmaf(v.z, v.z, s); s = fmaf(v.w, v.w, s);
    const uint16_t h0 = f2bf(v.x), h1 = f2bf(v.y), h2 = f2bf(v.z), h3 = f2bf(v.w);
    const uint16_t l0 = f2bf(v.x - bf2f(h0)), l1 = f2bf(v.y - bf2f(h1));
    const uint16_t l2 = f2bf(v.z - bf2f(h2)), l3 = f2bf(v.w - bf2f(h3));
    hb[2 * u]     = (uint32_t)h0 | ((uint32_t)h1 << 16);
    hb[2 * u + 1] = (uint32_t)h2 | ((uint32_t)h3 << 16);
    lb[2 * u]     = (uint32_t)l0 | ((uint32_t)l1 << 16);
    lb[2 * u + 1] = (uint32_t)l2 | ((uint32_t)l3 << 16);
  }
  uint32_t* dst = (uint32_t*)(Xs + (size_t)(m * N + i) * 128);
#pragma unroll
  for (int w = 0; w < 8; ++w) {
    uint4 qh = { hb[4 * w], hb[4 * w + 1], hb[4 * w + 2], hb[4 * w + 3] };
    ((uint4*)dst)[w] = qh;
  }
#pragma unroll
  for (int w = 0; w < 8; ++w) {
    uint4 ql = { lb[4 * w], lb[4 * w + 1], lb[4 * w + 2], lb[4 * w + 3] };
    ((uint4*)dst)[8 + w] = ql;
  }
  ysq[m * N + i] = s;
  inv[m * N + i] = 1.0f / (1.0f - fminf(s, 1.0f));
}

// K1: MFMA pairwise-z + per-row top-5 partials.
// One wave per block. Wave owns 16 rows x 512 cols (one col-eighth).
// dot = Ahi*Bhi + Ahi*Blo + Alo*Bhi via mfma_f32_16x16x32_bf16 (6 mfma/tile).
// grid (256 row-blocks, 8 eighths, 2 mods) = 4096 waves = 4 waves/SIMD.
// NOTE: no min-waves launch bound — round-4's (64,4) clamp spilled t5 to
// scratch (WRITE_SIZE 1.3->20.7 MB). Natural VGPR ~120 still gives 4/SIMD.
__global__ __launch_bounds__(64) void k_top5(
    const uint16_t* __restrict__ Xs, const float* __restrict__ ysq,
    const float* __restrict__ inv, uint64_t* __restrict__ partial) {
  const int m = blockIdx.z;
  const int qq = blockIdx.y;
  const int i0 = blockIdx.x * 16;
  const int j0q = qq * CQ;
  const int mN = m * N;
  const uint16_t* __restrict__ Xm = Xs + (size_t)m * N * 128;
  const int l = (int)threadIdx.x;
  const int lc = l & 15;          // A-row / B-col lane index
  const int lk = l >> 4;          // k-chunk group
  const int lk4 = lk * 4;         // C-row base for this lane
  const int lk8 = lk * 8;         // u16 offset of this lane's 8 bf16

  // A fragments: af[k-chunk][hi/lo]
  bf16x8 af[2][2];
#pragma unroll
  for (int c = 0; c < 2; ++c)
#pragma unroll
    for (int h = 0; h < 2; ++h)
      af[c][h] = *(const bf16x8*)(Xm + (size_t)(i0 + lc) * 128 +
                                  h * 64 + c * 32 + lk8);

  float xsq_r[4], inv_r[4];
#pragma unroll
  for (int p = 0; p < 4; ++p) {
    const int gi = i0 + lk4 + p;
    xsq_r[p] = ysq[mN + gi];
    inv_r[p] = inv[mN + gi];
  }

  // sentinel: z=+inf, idx=0xFFFFFFFF (never selected over any real z)
  const uint64_t SENT = ((uint64_t)0x7F800000u << 32) | 0xFFFFFFFFu;
  uint64_t t5[4][TOPK];
  float z5[4];
#pragma unroll
  for (int e = 0; e < 4; ++e) {
    z5[e] = __uint_as_float(0x7F800000u);   // +inf
#pragma unroll
    for (int t = 0; t < TOPK; ++t) t5[e][t] = SENT;
  }

  const f32x4 zz = {0.0f, 0.0f, 0.0f, 0.0f};

#define LOADB(BF, YC, IC, T)                                                   \
  {                                                                            \
    const uint16_t* bp = Xm + (size_t)(j0q + (T) * 16 + lc) * 128 + lk8;       \
    BF[0][0] = *(const bf16x8*)(bp);                                           \
    BF[1][0] = *(const bf16x8*)(bp + 32);                                      \
    BF[0][1] = *(const bf16x8*)(bp + 64);                                      \
    BF[1][1] = *(const bf16x8*)(bp + 96);                                      \
    YC = ysq[mN + j0q + (T) * 16 + lc];                                        \
    IC = inv[mN + j0q + (T) * 16 + lc];                                        \
  }

  // accumulation chain order identical to round-3 kernel (bit-exact)
#define MFMA_TILE(ACC, BF)                                                     \
  {                                                                            \
    ACC = __builtin_amdgcn_mfma_f32_16x16x32_bf16(af[0][0], BF[0][0], zz, 0, 0, 0);  \
    ACC = __builtin_amdgcn_mfma_f32_16x16x32_bf16(af[1][0], BF[1][0], ACC, 0, 0, 0); \
    ACC = __builtin_amdgcn_mfma_f32_16x16x32_bf16(af[0][0], BF[0][1], ACC, 0, 0, 0); \
    ACC = __builtin_amdgcn_mfma_f32_16x16x32_bf16(af[1][0], BF[1][1], ACC, 0, 0, 0); \
    ACC = __builtin_amdgcn_mfma_f32_16x16x32_bf16(af[0][1], BF[0][0], ACC, 0, 0, 0); \
    ACC = __builtin_amdgcn_mfma_f32_16x16x32_bf16(af[1][1], BF[1][0], ACC, 0, 0, 0); \
  }

#define EPILOG(T, ACC, YC, IC)                                                 \
  {                                                                            \
    const int gj = j0q + (T) * 16 + lc;                                        \
    _Pragma("unroll") for (int p = 0; p < 4; ++p) {                            \
      const int gi = i0 + lk4 + p;                                             \
      const float diff = fmaxf(xsq_r[p] + (YC)-2.0f * ACC[p], 0.0f);           \
      const float z = fmaf(2.0f * (diff * inv_r[p]), (IC), 1.0f);              \
      if (z <= z5[p] && gi != gj) {     /* fast screen vs 5th-best */          \
        uint64_t key = ((uint64_t)__float_as_uint(z) << 32) | (uint32_t)gj;    \
        if (key < t5[p][TOPK - 1]) {                                           \
          _Pragma("unroll") for (int tt = 0; tt < TOPK; ++tt) {                \
            const uint64_t cv = t5[p][tt];                                     \
            if (key < cv) { t5[p][tt] = key; key = cv; }                       \
          }                                                                    \
          z5[p] = __uint_as_float((uint32_t)(t5[p][TOPK - 1] >> 32));          \
        }                                                                      \
      }                                                                        \
    }                                                                          \
  }

  bf16x8 bE[2][2], bO[2][2];
  float ycE, icE, ycO, icO;
  f32x4 accE, accO;

  LOADB(bE, ycE, icE, 0)
  LOADB(bO, ycO, icO, 1)
  MFMA_TILE(accE, bE)

#pragma unroll 1
  for (int t = 1; t < NT; t += 2) {
    const float ycEp = ycE, icEp = icE;
    if (t + 1 < NT) LOADB(bE, ycE, icE, t + 1)
    MFMA_TILE(accO, bO)
    EPILOG(t - 1, accE, ycEp, icEp)
    const float ycOp = ycO, icOp = icO;
    if (t + 2 < NT) LOADB(bO, ycO, icO, t + 2)
    if (t + 1 < NT) MFMA_TILE(accE, bE)
    EPILOG(t, accO, ycOp, icOp)
  }
#undef LOADB
#undef MFMA_TILE
#undef EPILOG

  // cross-lane merge: row r = lk*4+p has 16 contributor lists (lc = 0..15)
  __shared__ uint64_t mbuf[16 * 81];   // stride 81 breaks bank alignment
#pragma unroll
  for (int p = 0; p < 4; ++p)
#pragma unroll
    for (int t = 0; t < TOPK; ++t)
      mbuf[(lk4 + p) * 81 + lc * TOPK + t] = t5[p][t];
  __syncthreads();

  if (l < 16) {
    uint64_t cur[TOPK];
#pragma unroll
    for (int t = 0; t < TOPK; ++t) cur[t] = mbuf[l * 81 + t];
    for (int c = 1; c < 16; ++c) {
      for (int t = 0; t < TOPK; ++t) {
        uint64_t key = mbuf[l * 81 + c * TOPK + t];
        if (key >= cur[TOPK - 1]) break;   // lists sorted ascending
#pragma unroll
        for (int u = 0; u < TOPK; ++u) {
          const uint64_t cv = cur[u];
          if (key < cv) { cur[u] = key; key = cv; }
        }
      }
    }
#pragma unroll
    for (int t = 0; t < TOPK; ++t)
      partial[((size_t)(m * NQ + qq) * N + i0 + l) * TOPK + t] = cur[t];
  }
}

// K2: merge eighth-partials -> top5; exact f32 pos_term recompute;
// threefry sampling + exact negative distances + logsumexp.
__global__ __launch_bounds__(64) void k_neg(const float* __restrict__ Xa,
                                            const float* __restrict__ Xt,
                                            const float* __restrict__ ysq,
                                            const float* __restrict__ inv,
                                            const uint64_t* __restrict__ partial,
                                            float* __restrict__ rowres) {
  const int m = blockIdx.y;
  const int i = blockIdx.x;
  const float* __restrict__ X = (m == 0) ? Xt : Xa;
  const uint32_t seed = (m == 0) ? 1u : 2u;  // key(1)=text, key(2)=audio
  const int lane = threadIdx.x;

  __shared__ float4 xi4[DIM / 4];
  __shared__ float posv[TOPK];
  if (lane < DIM / 4) xi4[lane] = ((const float4*)(X + (size_t)i * DIM))[lane];
  __syncthreads();

  // merge NQ sorted eighth lists (uniform across lanes)
  uint64_t cur[TOPK];
#pragma unroll
  for (int t = 0; t < TOPK; ++t)
    cur[t] = partial[((size_t)(m * NQ) * N + i) * TOPK + t];
  for (int q = 1; q < NQ; ++q) {
    for (int t = 0; t < TOPK; ++t) {
      uint64_t key = partial[((size_t)(m * NQ + q) * N + i) * TOPK + t];
      if (key >= cur[TOPK - 1]) break;
#pragma unroll
      for (int u = 0; u < TOPK; ++u) {
        const uint64_t cv = cur[u];
        if (key < cv) { cur[u] = key; key = cv; }
      }
    }
  }

  const float ysq_i = ysq[m * N + i];
  const float inv_i = inv[m * N + i];

  // lanes 32..36: exact f32 distance for the 5 selected positives
  if (lane >= 32 && lane < 32 + TOPK) {
    const int t = lane - 32;
    const uint32_t c = (uint32_t)(cur[t] & 0xffffffffu);
    const float4* xc = (const float4*)(X + (size_t)c * DIM);
    float dot = 0.0f;
#pragma unroll
    for (int k = 0; k < DIM / 4; ++k) {
      const float4 a = xi4[k];
      const float4 b = xc[k];
      dot = fmaf(a.x, b.x, dot); dot = fmaf(a.y, b.y, dot);
      dot = fmaf(a.z, b.z, dot); dot = fmaf(a.w, b.w, dot);
    }
    const float diff = fmaxf(ysq_i + ysq[m * N + c] - 2.0f * dot, 0.0f);
    const float z = 1.0f + 2.0f * diff * inv_i * inv[m * N + c];
    posv[t] = -acosh_dev(z) / TAU_;
  }

  uint32_t pidx[TOPK];
#pragma unroll
  for (int t = 0; t < TOPK; ++t) pidx[t] = (uint32_t)(cur[t] & 0xffffffffu);

#define CSWAP(a, b)                                                           \
  { const uint32_t mn = pidx[a] < pidx[b] ? pidx[a] : pidx[b];                \
    const uint32_t mx = pidx[a] < pidx[b] ? pidx[b] : pidx[a];                \
    pidx[a] = mn; pidx[b] = mx; }
  CSWAP(0, 1) CSWAP(3, 4) CSWAP(2, 4) CSWAP(2, 3) CSWAP(1, 4)
  CSWAP(0, 3) CSWAP(0, 2) CSWAP(1, 3) CSWAP(1, 2)
#undef CSWAP

  float v = -1e30f;
  if (lane < NEGS) {
    const uint32_t f = (uint32_t)i * (uint32_t)NEGS + (uint32_t)lane;
    uint32_t c = sample_idx(seed, f);
#pragma unroll
    for (int t = 0; t < TOPK; ++t) c += (c >= pidx[t]) ? 1u : 0u;
    if (c != (uint32_t)i) {
      const float4* xc = (const float4*)(X + (size_t)c * DIM);
      float dot = 0.0f;
#pragma unroll
      for (int k = 0; k < DIM / 4; ++k) {
        const float4 a = xi4[k];
        const float4 b = xc[k];
        dot = fmaf(a.x, b.x, dot); dot = fmaf(a.y, b.y, dot);
        dot = fmaf(a.z, b.z, dot); dot = fmaf(a.w, b.w, dot);
      }
      const float diff = fmaxf(ysq_i + ysq[m * N + c] - 2.0f * dot, 0.0f);
      const float z = 1.0f + 2.0f * diff * inv_i * inv[m * N + c];
      v = -acosh_dev(z) / TAU_;
    }
  }

  __syncthreads();   // posv visible

  float vmax = v;
#pragma unroll
  for (int o = 32; o > 0; o >>= 1) vmax = fmaxf(vmax, __shfl_xor(vmax, o, 64));
  float e = expf(v - vmax);
  float ss = e;
#pragma unroll
  for (int o = 32; o > 0; o >>= 1) ss += __shfl_xor(ss, o, 64);

  if (lane == 0) {
    float vm = -1e30f;
#pragma unroll
    for (int t = 0; t < TOPK; ++t) vm = fmaxf(vm, posv[t]);
    float ps = 0.0f;
#pragma unroll
    for (int t = 0; t < TOPK; ++t) ps += expf(posv[t] - vm);
    const float pos = vm + logf(ps);
    rowres[m * N + i] = (vmax + logf(ss)) - pos;
  }
}

// K3: deterministic final reduce (f64 accumulation), out = 0.01 * mean
__global__ __launch_bounds__(256) void k_reduce(const float* __restrict__ rowres,
                                                float* __restrict__ out) {
  __shared__ double sh[256];
  double s = 0.0;
  for (int idx = threadIdx.x; idx < 2 * N; idx += 256) s += (double)rowres[idx];
  sh[threadIdx.x] = s;
  __syncthreads();
  for (int o = 128; o > 0; o >>= 1) {
    if (threadIdx.x < o) sh[threadIdx.x] += sh[threadIdx.x + o];
    __syncthreads();
  }
  if (threadIdx.x == 0) out[0] = (float)(0.01 * (sh[0] / (double)N));
}

extern "C" void kernel_launch(void* const* d_in, const int* in_sizes, int n_in,
                              void* d_out, int out_size, void* d_ws,
                              size_t ws_size, hipStream_t stream) {
  const float* Xa = (const float*)d_in[0];   // audio_embeds
  const float* Xt = (const float*)d_in[1];   // text_embeds
  float* out = (float*)d_out;

  // ws layout (~4.8 MB): ysq[2N] | inv[2N] | partial[2*NQ*N*5 u64] | rowres[2N]
  //                      | Xs[2*N*128 u16]
  float* ysq = (float*)d_ws;
  float* inv = ysq + 2 * N;
  uint64_t* partial = (uint64_t*)(inv + 2 * N);
  float* rowres = (float*)(partial + (size_t)2 * NQ * N * TOPK);
  uint16_t* Xs = (uint16_t*)(rowres + 2 * N);

  k_pre<<<dim3(N / 64, 2), 64, 0, stream>>>(Xa, Xt, Xs, ysq, inv);
  k_top5<<<dim3(N / 16, NQ, 2), 64, 0, stream>>>(Xs, ysq, inv, partial);
  k_neg<<<dim3(N, 2), 64, 0, stream>>>(Xa, Xt, ysq, inv, partial, rowres);
  k_reduce<<<1, 256, 0, stream>>>(rowres, out);
}

// Round 7
// 131.654 us; speedup vs baseline: 1.3293x; 1.0030x over previous
//
#include <hip/hip_runtime.h>
#include <stdint.h>

#define JAX_PARTITIONABLE 1

constexpr int N = 4096;
constexpr int DIM = 64;
constexpr int TOPK = 5;
constexpr int NEGS = 20;
constexpr float TAU_ = 0.1f;
constexpr uint32_t SPAN = 4091u;   // N - TOPK
constexpr uint32_t MULT = 2309u;   // ((1<<16) % SPAN)^2 % SPAN

constexpr int CQ = 256;            // cols per wave slab
constexpr int NQ = N / CQ;         // 16 col groups
constexpr int NT = CQ / 16;        // 16 tiles per wave

typedef __attribute__((ext_vector_type(8))) short bf16x8;
typedef __attribute__((ext_vector_type(4))) float f32x4;

__device__ __forceinline__ uint32_t rotl32(uint32_t v, int d) {
  return (v << d) | (v >> (32 - d));
}

// Threefry-2x32, 20 rounds, exactly as jax/_src/prng.py lowering.
__device__ __forceinline__ void threefry(uint32_t k0, uint32_t k1,
                                         uint32_t& x0, uint32_t& x1) {
  const uint32_t k2 = k0 ^ k1 ^ 0x1BD11BDAu;
  x0 += k0; x1 += k1;
#define TF_R(r) { x0 += x1; x1 = rotl32(x1, r); x1 ^= x0; }
  TF_R(13) TF_R(15) TF_R(26) TF_R(6)
  x0 += k1; x1 += k2 + 1u;
  TF_R(17) TF_R(29) TF_R(16) TF_R(24)
  x0 += k2; x1 += k0 + 2u;
  TF_R(13) TF_R(15) TF_R(26) TF_R(6)
  x0 += k0; x1 += k1 + 3u;
  TF_R(17) TF_R(29) TF_R(16) TF_R(24)
  x0 += k1; x1 += k2 + 4u;
  TF_R(13) TF_R(15) TF_R(26) TF_R(6)
  x0 += k2; x1 += k0 + 5u;
#undef TF_R
}

__device__ __forceinline__ uint32_t sample_idx(uint32_t seed, uint32_t f) {
#if JAX_PARTITIONABLE
  uint32_t a0 = 0u, a1 = 0u; threefry(0u, seed, a0, a1);   // k1 = enc(key,(0,0))
  uint32_t b0 = 0u, b1 = 1u; threefry(0u, seed, b0, b1);   // k2 = enc(key,(0,1))
  uint32_t h0 = 0u, h1 = f;  threefry(a0, a1, h0, h1);
  const uint32_t hi = h0 ^ h1;
  uint32_t l0 = 0u, l1 = f;  threefry(b0, b1, l0, l1);
  const uint32_t lo = l0 ^ l1;
#else
  uint32_t a0 = 0u, a1 = 2u; threefry(0u, seed, a0, a1);
  uint32_t c0 = 1u, c1 = 3u; threefry(0u, seed, c0, c1);
  const uint32_t HALF = (uint32_t)(N * NEGS / 2);
  uint32_t hi, lo;
  if (f < HALF) {
    uint32_t x0 = f, x1 = f + HALF; threefry(a0, c0, x0, x1); hi = x0;
    x0 = f; x1 = f + HALF;          threefry(a1, c1, x0, x1); lo = x0;
  } else {
    uint32_t x0 = f - HALF, x1 = f; threefry(a0, c0, x0, x1); hi = x1;
    x0 = f - HALF; x1 = f;          threefry(a1, c1, x0, x1); lo = x1;
  }
#endif
  return ((hi % SPAN) * MULT + (lo % SPAN)) % SPAN;
}

__device__ __forceinline__ float acosh_dev(float z) {
  return logf(z + sqrtf((z - 1.0f) * (z + 1.0f)));
}

__device__ __forceinline__ uint16_t f2bf(float f) {   // RNE f32 -> bf16
  const uint32_t u = __float_as_uint(f);
  return (uint16_t)((u + 0x7FFFu + ((u >> 16) & 1u)) >> 16);
}
__device__ __forceinline__ float bf2f(uint16_t h) {
  return __uint_as_float((uint32_t)h << 16);
}

// K_pre: per row: exact f32 norms + inv, and bf16 hi/lo split rows
// Xs layout: [mod][row][128 u16] = hi[64] | lo[64], row stride 256 B.
__global__ __launch_bounds__(64) void k_pre(const float* __restrict__ Xa,
                                            const float* __restrict__ Xt,
                                            uint16_t* __restrict__ Xs,
                                            float* __restrict__ ysq,
                                            float* __restrict__ inv) {
  const int m = blockIdx.y;                  // 0 = text, 1 = audio
  const float* __restrict__ X = (m == 0) ? Xt : Xa;
  const int i = blockIdx.x * 64 + threadIdx.x;
  const float* xr = X + (size_t)i * DIM;

  uint32_t hb[DIM / 2], lb[DIM / 2];
  float s = 0.0f;
#pragma unroll
  for (int u = 0; u < DIM / 4; ++u) {
    const float4 v = *(const float4*)(xr + 4 * u);
    s = fmaf(v.x, v.x, s); s = fmaf(v.y, v.y, s);
    s = fmaf(v.z, v.z, s); s = fmaf(v.w, v.w, s);
    const uint16_t h0 = f2bf(v.x), h1 = f2bf(v.y), h2 = f2bf(v.z), h3 = f2bf(v.w);
    const uint16_t l0 = f2bf(v.x - bf2f(h0)), l1 = f2bf(v.y - bf2f(h1));
    const uint16_t l2 = f2bf(v.z - bf2f(h2)), l3 = f2bf(v.w - bf2f(h3));
    hb[2 * u]     = (uint32_t)h0 | ((uint32_t)h1 << 16);
    hb[2 * u + 1] = (uint32_t)h2 | ((uint32_t)h3 << 16);
    lb[2 * u]     = (uint32_t)l0 | ((uint32_t)l1 << 16);
    lb[2 * u + 1] = (uint32_t)l2 | ((uint32_t)l3 << 16);
  }
  uint32_t* dst = (uint32_t*)(Xs + (size_t)(m * N + i) * 128);
#pragma unroll
  for (int w = 0; w < 8; ++w) {
    uint4 qh = { hb[4 * w], hb[4 * w + 1], hb[4 * w + 2], hb[4 * w + 3] };
    ((uint4*)dst)[w] = qh;
  }
#pragma unroll
  for (int w = 0; w < 8; ++w) {
    uint4 ql = { lb[4 * w], lb[4 * w + 1], lb[4 * w + 2], lb[4 * w + 3] };
    ((uint4*)dst)[8 + w] = ql;
  }
  ysq[m * N + i] = s;
  inv[m * N + i] = 1.0f / (1.0f - fminf(s, 1.0f));
}

// K1: MFMA pairwise-z + per-row top-5 partials (swapped-operand layout).
// mfma(Y_tile, X_rows): lane owns ONE output row (lc) and 4 cols (lk4+p).
// Per-thread: ONE top-5 list (10 VGPR). Cross-lane exact screen tau =
// min over the row's 4 lk-lanes of their 5th-best (any z > tau is dominated
// by >=5 same-row values -> safe to drop).  2 waves/block, 16 rows/wave,
// CQ=256 cols/wave.  grid (128, 16, 2) = 8192 waves.
__global__ __launch_bounds__(128) void k_top5(
    const uint16_t* __restrict__ Xs, const float* __restrict__ ysq,
    const float* __restrict__ inv, uint64_t* __restrict__ partial) {
  const int m = blockIdx.z;
  const int qq = blockIdx.y;
  const int wid = (int)threadIdx.x >> 6;
  const int l = (int)threadIdx.x & 63;
  const int i0 = (blockIdx.x * 2 + wid) * 16;
  const int j0q = qq * CQ;
  const int mN = m * N;
  const uint16_t* __restrict__ Xm = Xs + (size_t)m * N * 128;
  const int lc = l & 15;          // output row index (this lane's row)
  const int lk = l >> 4;
  const int lk4 = lk * 4;         // candidate-col base for this lane
  const int lk8 = lk * 8;        // u16 offset of this lane's 8 bf16 (k-slice)

  // B operand: X rows (fixed): xf[k-chunk][hi/lo]
  bf16x8 xf[2][2];
#pragma unroll
  for (int c = 0; c < 2; ++c)
#pragma unroll
    for (int h = 0; h < 2; ++h)
      xf[c][h] = *(const bf16x8*)(Xm + (size_t)(i0 + lc) * 128 +
                                  h * 64 + c * 32 + lk8);

  const float xsq_i = ysq[mN + i0 + lc];
  const float inv_i = inv[mN + i0 + lc];
  const int gi = i0 + lc;

  // sentinel: z=+inf, idx=0xFFFFFFFF
  const uint64_t SENT = ((uint64_t)0x7F800000u << 32) | 0xFFFFFFFFu;
  uint64_t t5[TOPK];
#pragma unroll
  for (int t = 0; t < TOPK; ++t) t5[t] = SENT;

  const f32x4 zz = {0.0f, 0.0f, 0.0f, 0.0f};
  const float INF_ = __uint_as_float(0x7F800000u);

#pragma unroll 1
  for (int T = 0; T < NT; ++T) {
    // exact screen: tau = min over same-row lanes (xor 16,32) of 5th-best z
    float w = __uint_as_float((uint32_t)(t5[TOPK - 1] >> 32));
    w = fminf(w, __shfl_xor(w, 16, 64));
    const float tau = fminf(w, __shfl_xor(w, 32, 64));

    const int jb = j0q + T * 16;
    const uint16_t* yp = Xm + (size_t)(jb + lc) * 128 + lk8;
    const bf16x8 y00 = *(const bf16x8*)(yp);        // Y hi k0
    const bf16x8 y10 = *(const bf16x8*)(yp + 32);   // Y hi k1
    const bf16x8 y01 = *(const bf16x8*)(yp + 64);   // Y lo k0
    const bf16x8 y11 = *(const bf16x8*)(yp + 96);   // Y lo k1
    const float4 ysq4 = *(const float4*)&ysq[mN + jb + lk4];
    const float4 inv4 = *(const float4*)&inv[mN + jb + lk4];

    // same term order as rounds 3-5 (bit-exact z):
    f32x4 acc;
    acc = __builtin_amdgcn_mfma_f32_16x16x32_bf16(y00, xf[0][0], zz, 0, 0, 0);
    acc = __builtin_amdgcn_mfma_f32_16x16x32_bf16(y10, xf[1][0], acc, 0, 0, 0);
    acc = __builtin_amdgcn_mfma_f32_16x16x32_bf16(y01, xf[0][0], acc, 0, 0, 0);
    acc = __builtin_amdgcn_mfma_f32_16x16x32_bf16(y11, xf[1][0], acc, 0, 0, 0);
    acc = __builtin_amdgcn_mfma_f32_16x16x32_bf16(y00, xf[0][1], acc, 0, 0, 0);
    acc = __builtin_amdgcn_mfma_f32_16x16x32_bf16(y10, xf[1][1], acc, 0, 0, 0);

    float zt[4];
#pragma unroll
    for (int p = 0; p < 4; ++p) {
      const float yc = (p == 0) ? ysq4.x : (p == 1) ? ysq4.y
                      : (p == 2) ? ysq4.z : ysq4.w;
      const float ic = (p == 0) ? inv4.x : (p == 1) ? inv4.y
                      : (p == 2) ? inv4.z : inv4.w;
      const float diff = fmaxf(xsq_i + yc - 2.0f * acc[p], 0.0f);
      const float z = fmaf(2.0f * (diff * inv_i), ic, 1.0f);
      zt[p] = (gi == jb + lk4 + p) ? INF_ : z;   // diagonal -> never selected
    }
    const float zm = fminf(fminf(zt[0], zt[1]), fminf(zt[2], zt[3]));
    if (zm <= tau) {
#pragma unroll
      for (int p = 0; p < 4; ++p) {
        uint64_t key = ((uint64_t)__float_as_uint(zt[p]) << 32) |
                       (uint32_t)(jb + lk4 + p);
        if (key < t5[TOPK - 1]) {
#pragma unroll
          for (int tt = 0; tt < TOPK; ++tt) {
            const uint64_t cv = t5[tt];
            if (key < cv) { t5[tt] = key; key = cv; }
          }
        }
      }
    }
  }

  // merge: row lc has 4 lists (lanes lk*16+lc).  LDS: [wave][row][4*5+1]
  __shared__ uint64_t mbuf[2][16][21];
#pragma unroll
  for (int t = 0; t < TOPK; ++t) mbuf[wid][lc][lk * TOPK + t] = t5[t];
  __syncthreads();

  if (l < 16) {
    uint64_t cur[TOPK];
#pragma unroll
    for (int t = 0; t < TOPK; ++t) cur[t] = mbuf[wid][l][t];
    for (int c = 1; c < 4; ++c) {
      for (int t = 0; t < TOPK; ++t) {
        uint64_t key = mbuf[wid][l][c * TOPK + t];
        if (key >= cur[TOPK - 1]) break;   // lists sorted ascending
#pragma unroll
        for (int u = 0; u < TOPK; ++u) {
          const uint64_t cv = cur[u];
          if (key < cv) { cur[u] = key; key = cv; }
        }
      }
    }
#pragma unroll
    for (int t = 0; t < TOPK; ++t)
      partial[((size_t)(m * NQ + qq) * N + i0 + l) * TOPK + t] = cur[t];
  }
}

// K2: merge slab-partials -> top5; exact f32 pos_term recompute;
// threefry sampling + exact negative distances + logsumexp.
__global__ __launch_bounds__(64) void k_neg(const float* __restrict__ Xa,
                                            const float* __restrict__ Xt,
                                            const float* __restrict__ ysq,
                                            const float* __restrict__ inv,
                                            const uint64_t* __restrict__ partial,
                                            float* __restrict__ rowres) {
  const int m = blockIdx.y;
  const int i = blockIdx.x;
  const float* __restrict__ X = (m == 0) ? Xt : Xa;
  const uint32_t seed = (m == 0) ? 1u : 2u;  // key(1)=text, key(2)=audio
  const int lane = threadIdx.x;

  __shared__ float4 xi4[DIM / 4];
  __shared__ float posv[TOPK];
  if (lane < DIM / 4) xi4[lane] = ((const float4*)(X + (size_t)i * DIM))[lane];
  __syncthreads();

  // merge NQ sorted lists (uniform across lanes)
  uint64_t cur[TOPK];
#pragma unroll
  for (int t = 0; t < TOPK; ++t)
    cur[t] = partial[((size_t)(m * NQ) * N + i) * TOPK + t];
  for (int q = 1; q < NQ; ++q) {
    for (int t = 0; t < TOPK; ++t) {
      uint64_t key = partial[((size_t)(m * NQ + q) * N + i) * TOPK + t];
      if (key >= cur[TOPK - 1]) break;
#pragma unroll
      for (int u = 0; u < TOPK; ++u) {
        const uint64_t cv = cur[u];
        if (key < cv) { cur[u] = key; key = cv; }
      }
    }
  }

  const float ysq_i = ysq[m * N + i];
  const float inv_i = inv[m * N + i];

  // lanes 32..36: exact f32 distance for the 5 selected positives
  if (lane >= 32 && lane < 32 + TOPK) {
    const int t = lane - 32;
    const uint32_t c = (uint32_t)(cur[t] & 0xffffffffu);
    const float4* xc = (const float4*)(X + (size_t)c * DIM);
    float dot = 0.0f;
#pragma unroll
    for (int k = 0; k < DIM / 4; ++k) {
      const float4 a = xi4[k];
      const float4 b = xc[k];
      dot = fmaf(a.x, b.x, dot); dot = fmaf(a.y, b.y, dot);
      dot = fmaf(a.z, b.z, dot); dot = fmaf(a.w, b.w, dot);
    }
    const float diff = fmaxf(ysq_i + ysq[m * N + c] - 2.0f * dot, 0.0f);
    const float z = 1.0f + 2.0f * diff * inv_i * inv[m * N + c];
    posv[t] = -acosh_dev(z) / TAU_;
  }

  uint32_t pidx[TOPK];
#pragma unroll
  for (int t = 0; t < TOPK; ++t) pidx[t] = (uint32_t)(cur[t] & 0xffffffffu);

#define CSWAP(a, b)                                                           \
  { const uint32_t mn = pidx[a] < pidx[b] ? pidx[a] : pidx[b];                \
    const uint32_t mx = pidx[a] < pidx[b] ? pidx[b] : pidx[a];                \
    pidx[a] = mn; pidx[b] = mx; }
  CSWAP(0, 1) CSWAP(3, 4) CSWAP(2, 4) CSWAP(2, 3) CSWAP(1, 4)
  CSWAP(0, 3) CSWAP(0, 2) CSWAP(1, 3) CSWAP(1, 2)
#undef CSWAP

  float v = -1e30f;
  if (lane < NEGS) {
    const uint32_t f = (uint32_t)i * (uint32_t)NEGS + (uint32_t)lane;
    uint32_t c = sample_idx(seed, f);
#pragma unroll
    for (int t = 0; t < TOPK; ++t) c += (c >= pidx[t]) ? 1u : 0u;
    if (c != (uint32_t)i) {
      const float4* xc = (const float4*)(X + (size_t)c * DIM);
      float dot = 0.0f;
#pragma unroll
      for (int k = 0; k < DIM / 4; ++k) {
        const float4 a = xi4[k];
        const float4 b = xc[k];
        dot = fmaf(a.x, b.x, dot); dot = fmaf(a.y, b.y, dot);
        dot = fmaf(a.z, b.z, dot); dot = fmaf(a.w, b.w, dot);
      }
      const float diff = fmaxf(ysq_i + ysq[m * N + c] - 2.0f * dot, 0.0f);
      const float z = 1.0f + 2.0f * diff * inv_i * inv[m * N + c];
      v = -acosh_dev(z) / TAU_;
    }
  }

  __syncthreads();   // posv visible

  float vmax = v;
#pragma unroll
  for (int o = 32; o > 0; o >>= 1) vmax = fmaxf(vmax, __shfl_xor(vmax, o, 64));
  float e = expf(v - vmax);
  float ss = e;
#pragma unroll
  for (int o = 32; o > 0; o >>= 1) ss += __shfl_xor(ss, o, 64);

  if (lane == 0) {
    float vm = -1e30f;
#pragma unroll
    for (int t = 0; t < TOPK; ++t) vm = fmaxf(vm, posv[t]);
    float ps = 0.0f;
#pragma unroll
    for (int t = 0; t < TOPK; ++t) ps += expf(posv[t] - vm);
    const float pos = vm + logf(ps);
    rowres[m * N + i] = (vmax + logf(ss)) - pos;
  }
}

// K3: deterministic final reduce (f64 accumulation), out = 0.01 * mean
__global__ __launch_bounds__(256) void k_reduce(const float* __restrict__ rowres,
                                                float* __restrict__ out) {
  __shared__ double sh[256];
  double s = 0.0;
  for (int idx = threadIdx.x; idx < 2 * N; idx += 256) s += (double)rowres[idx];
  sh[threadIdx.x] = s;
  __syncthreads();
  for (int o = 128; o > 0; o >>= 1) {
    if (threadIdx.x < o) sh[threadIdx.x] += sh[threadIdx.x + o];
    __syncthreads();
  }
  if (threadIdx.x == 0) out[0] = (float)(0.01 * (sh[0] / (double)N));
}

extern "C" void kernel_launch(void* const* d_in, const int* in_sizes, int n_in,
                              void* d_out, int out_size, void* d_ws,
                              size_t ws_size, hipStream_t stream) {
  const float* Xa = (const float*)d_in[0];   // audio_embeds
  const float* Xt = (const float*)d_in[1];   // text_embeds
  float* out = (float*)d_out;

  // ws layout (~7.4 MB): ysq[2N] | inv[2N] | partial[2*NQ*N*5 u64] | rowres[2N]
  //                      | Xs[2*N*128 u16]
  float* ysq = (float*)d_ws;
  float* inv = ysq + 2 * N;
  uint64_t* partial = (uint64_t*)(inv + 2 * N);
  float* rowres = (float*)(partial + (size_t)2 * NQ * N * TOPK);
  uint16_t* Xs = (uint16_t*)(rowres + 2 * N);

  k_pre<<<dim3(N / 64, 2), 64, 0, stream>>>(Xa, Xt, Xs, ysq, inv);
  k_top5<<<dim3(N / 32, NQ, 2), 128, 0, stream>>>(Xs, ysq, inv, partial);
  k_neg<<<dim3(N, 2), 64, 0, stream>>>(Xa, Xt, ysq, inv, partial, rowres);
  k_reduce<<<1, 256, 0, stream>>>(rowres, out);
}